// Round 17
// baseline (198.253 us; speedup 1.0000x reference)
//
#include <hip/hip_runtime.h>

typedef short short8 __attribute__((ext_vector_type(8)));
typedef short short4v __attribute__((ext_vector_type(4)));
typedef float f32x4 __attribute__((ext_vector_type(4)));
typedef unsigned uint2v __attribute__((ext_vector_type(2)));

__device__ __forceinline__ float bf2f(short b) {
  unsigned u = ((unsigned)(unsigned short)b) << 16;
  return __builtin_bit_cast(float, u);
}
__device__ __forceinline__ short f2bf(float f) {
  unsigned u = __builtin_bit_cast(unsigned, f);
  u += 0x7fffu + ((u >> 16) & 1u);
  return (short)(u >> 16);
}
__device__ __forceinline__ unsigned cvt_pk_bf16(float lo, float hi) {
  unsigned r;
  asm("v_cvt_pk_bf16_f32 %0, %1, %2" : "=v"(r) : "v"(lo), "v"(hi));
  return r;
}

__device__ __forceinline__ void gload_lds16(const void* g, void* l) {
  __builtin_amdgcn_global_load_lds(
      (const __attribute__((address_space(1))) unsigned int*)g,
      (__attribute__((address_space(3))) unsigned int*)l, 16, 0, 0);
}

// swizzled LDS fragment read: tile rows of 64 shorts (128B), chunk = 16B unit,
// physical chunk = logical chunk ^ (row & 7)  [T2 involution]
__device__ __forceinline__ short8 lds_frag(const short* tile, int row, int kc, int l4) {
  int chunk = (kc * 4 + l4) ^ (row & 7);
  return *(const short8*)&tile[row * 64 + chunk * 8];
}

// ---------------- fp32 -> bf16 convert (x) ----------------
__global__ __launch_bounds__(256) void k_convert_bf16(const float* __restrict__ in,
                                                      short* __restrict__ out, int n8) {
  int i = blockIdx.x * 256 + threadIdx.x;
  if (i >= n8) return;
  const float4* p = (const float4*)in;
  float4 a = p[2 * i], b = p[2 * i + 1];
  short8 o;
  o[0] = f2bf(a.x); o[1] = f2bf(a.y); o[2] = f2bf(a.z); o[3] = f2bf(a.w);
  o[4] = f2bf(b.x); o[5] = f2bf(b.y); o[6] = f2bf(b.z); o[7] = f2bf(b.w);
  ((short8*)out)[i] = o;
}

// ---------------- weight transpose+convert: w[K][N] f32 -> wT[N][K] bf16 ----------------
__global__ __launch_bounds__(256) void k_transpose_w(const float* __restrict__ w,
                                                     short* __restrict__ wT, int K, int N) {
  __shared__ float t[32][33];
  int nt = N >> 5;
  int rt = blockIdx.x / nt, ct = blockIdx.x % nt;
  int tx = threadIdx.x & 31, ty = threadIdx.x >> 5;
#pragma unroll
  for (int i = 0; i < 4; ++i) {
    int r = ty * 4 + i;
    t[r][tx] = w[(size_t)(rt * 32 + r) * N + ct * 32 + tx];
  }
  __syncthreads();
#pragma unroll
  for (int i = 0; i < 4; ++i) {
    int r = ty * 4 + i;
    wT[(size_t)(ct * 32 + r) * K + rt * 32 + tx] = f2bf(t[tx][r]);
  }
}

// ---------------- GEMM 256x128, BK=64, 8-phase, race-free in-place staging ----------------
// BN=128 variant of the verified r10 template (fixes grid quantization: GEMM1 768 blocks =
// 3.0/CU, GEMM2 256 blocks = 1.0/CU). 8 waves (2Mx4N), per-wave 128x32 output, LDS 96KB.
// Liveness: bflo cached ph1->ph4; B LDS reads end ph2 -> stage B(t+2)@ph3 (2 loads);
// A reads end ph3 -> stage A(t+2)@ph4 (4 loads). 6 loads/tile/wave -> steady vmcnt(6).
// BF16OUT (GEMM1): cols >= 2048 (V part) written transposed into vT[bh][d][tok].
template <bool BF16OUT>
__global__ __launch_bounds__(512, 1) void k_gemm8p(const short* __restrict__ A,
                                                   const short* __restrict__ Bt,
                                                   const float* __restrict__ bias,
                                                   void* __restrict__ Cout,
                                                   short* __restrict__ vTout,
                                                   int M, int N, int K) {
  __shared__ __align__(16) short Ab[2][256 * 64];
  __shared__ __align__(16) short Bb[2][128 * 64];
  int nt = N >> 7;
  int nwg = gridDim.x;
  int bid = blockIdx.x;
  int swz = (bid & 7) * (nwg >> 3) + (bid >> 3);  // nwg % 8 == 0 -> bijective
  int mt = swz / nt, ct = swz % nt;
  int tid = threadIdx.x, w = tid >> 6, lane = tid & 63;
  int l15 = lane & 15, l4 = lane >> 4;
  int wm = w >> 2, wn = w & 3;
  const short* Abase = A + (size_t)mt * 256 * K;
  const short* Bbase = Bt + (size_t)ct * 128 * K;
  int NT = K >> 6;

  int srow = lane >> 3;
  int slc = (lane & 7) ^ srow;  // pre-swizzled source chunk (involution partner of read XOR)

  // stage one 128-row half (A: half 0/1; B: half 0 only): linear LDS dest, swizzled source
  auto stage = [&](const short* gbase, short* dstTile, int kt, int half) {
#pragma unroll
    for (int i = 0; i < 2; ++i) {
      int rowg = half * 128 + i * 64 + w * 8;
      gload_lds16(gbase + (size_t)(rowg + srow) * K + kt * 64 + slc * 8,
                  dstTile + (size_t)rowg * 64);
    }
  };

  f32x4 acc[8][2];
#pragma unroll
  for (int m = 0; m < 8; ++m)
#pragma unroll
    for (int n = 0; n < 2; ++n) acc[m][n] = f32x4{0.f, 0.f, 0.f, 0.f};

  // prologue: tiles 0 and 1 fully staged (6 loads each); wait tile0 (tile1's 6 in flight)
  stage(Bbase, &Bb[0][0], 0, 0);
  stage(Abase, &Ab[0][0], 0, 0);
  stage(Abase, &Ab[0][0], 0, 1);
  stage(Bbase, &Bb[1][0], 1, 0);
  stage(Abase, &Ab[1][0], 1, 0);
  stage(Abase, &Ab[1][0], 1, 1);
  asm volatile("s_waitcnt vmcnt(6)" ::: "memory");
  __builtin_amdgcn_s_barrier();

  for (int t = 0; t < NT; ++t) {
    int b = t & 1;
    const short* At = &Ab[b][0];
    const short* Btl = &Bb[b][0];
    short* Aw = &Ab[b][0];
    short* Bw = &Bb[b][0];
    bool pre = (t + 2 < NT);

    short8 aflo[4][2], bflo[2], bfhi[2], afhi[4][2];

    // ===== phase 1: m-lo x n-lo (bflo cached for ph4) =====
#pragma unroll
    for (int mq = 0; mq < 4; ++mq)
#pragma unroll
      for (int kc = 0; kc < 2; ++kc)
        aflo[mq][kc] = lds_frag(At, wm * 128 + mq * 16 + l15, kc, l4);
#pragma unroll
    for (int kc = 0; kc < 2; ++kc)
      bflo[kc] = lds_frag(Btl, wn * 32 + l15, kc, l4);
    __builtin_amdgcn_s_barrier();
    asm volatile("s_waitcnt lgkmcnt(0)" ::: "memory");
    __builtin_amdgcn_sched_barrier(0);
    __builtin_amdgcn_s_setprio(1);
#pragma unroll
    for (int mq = 0; mq < 4; ++mq)
#pragma unroll
      for (int kc = 0; kc < 2; ++kc)
        acc[mq][0] = __builtin_amdgcn_mfma_f32_16x16x32_bf16(aflo[mq][kc], bflo[kc], acc[mq][0], 0, 0, 0);
    __builtin_amdgcn_s_setprio(0);
    __builtin_amdgcn_s_barrier();

    // ===== phase 2: m-lo x n-hi =====
#pragma unroll
    for (int kc = 0; kc < 2; ++kc)
      bfhi[kc] = lds_frag(Btl, wn * 32 + 16 + l15, kc, l4);
    __builtin_amdgcn_s_barrier();
    asm volatile("s_waitcnt lgkmcnt(0)" ::: "memory");
    __builtin_amdgcn_sched_barrier(0);
    __builtin_amdgcn_s_setprio(1);
#pragma unroll
    for (int mq = 0; mq < 4; ++mq)
#pragma unroll
      for (int kc = 0; kc < 2; ++kc)
        acc[mq][1] = __builtin_amdgcn_mfma_f32_16x16x32_bf16(aflo[mq][kc], bfhi[kc], acc[mq][1], 0, 0, 0);
    __builtin_amdgcn_s_setprio(0);
    __builtin_amdgcn_s_barrier();  // ph2-end: ALL B reads of tile t complete

    // ===== phase 3: m-hi x n-hi; stage B(t+2) in place (B region free) =====
#pragma unroll
    for (int mq = 0; mq < 4; ++mq)
#pragma unroll
      for (int kc = 0; kc < 2; ++kc)
        afhi[mq][kc] = lds_frag(At, wm * 128 + 64 + mq * 16 + l15, kc, l4);
    if (pre) stage(Bbase, Bw, t + 2, 0);
    __builtin_amdgcn_s_barrier();
    asm volatile("s_waitcnt lgkmcnt(0)" ::: "memory");
    __builtin_amdgcn_sched_barrier(0);
    __builtin_amdgcn_s_setprio(1);
#pragma unroll
    for (int mq = 0; mq < 4; ++mq)
#pragma unroll
      for (int kc = 0; kc < 2; ++kc)
        acc[4 + mq][1] = __builtin_amdgcn_mfma_f32_16x16x32_bf16(afhi[mq][kc], bfhi[kc], acc[4 + mq][1], 0, 0, 0);
    __builtin_amdgcn_s_setprio(0);
    __builtin_amdgcn_s_barrier();  // ph3-end: ALL A reads of tile t complete

    // ===== phase 4: m-hi x n-lo (register reuse); stage A(t+2) in place =====
    if (pre) {
      stage(Abase, Aw, t + 2, 0);
      stage(Abase, Aw, t + 2, 1);
    }
    __builtin_amdgcn_s_setprio(1);
#pragma unroll
    for (int mq = 0; mq < 4; ++mq)
#pragma unroll
      for (int kc = 0; kc < 2; ++kc)
        acc[4 + mq][0] = __builtin_amdgcn_mfma_f32_16x16x32_bf16(afhi[mq][kc], bflo[kc], acc[4 + mq][0], 0, 0, 0);
    __builtin_amdgcn_s_setprio(0);
    // counted wait: drain tile t+1's 6 loads, keep tile t+2's 6 in flight
    if (pre) {
      asm volatile("s_waitcnt vmcnt(6)" ::: "memory");
    } else if (t + 1 < NT) {
      asm volatile("s_waitcnt vmcnt(0)" ::: "memory");
    }
    __builtin_amdgcn_s_barrier();
  }

  // epilogue
#pragma unroll
  for (int m = 0; m < 8; ++m) {
#pragma unroll
    for (int n = 0; n < 2; ++n) {
      int row = mt * 256 + wm * 128 + m * 16 + l4 * 4;
      int col = ct * 128 + wn * 32 + n * 16 + l15;
      float bv = bias[col];
      if constexpr (BF16OUT) {
        short4v pk4;
#pragma unroll
        for (int j = 0; j < 4; ++j) pk4[j] = f2bf(acc[m][n][j] + bv);
        if (col >= 2048) {
          int hh = (col - 2048) >> 6, dd = (col - 2048) & 63;
          int batch2 = row >> 11, tok = row & 2047;
          *(short4v*)(vTout + (((size_t)(batch2 * 16 + hh) * 64 + dd) << 11) + tok) = pk4;
        } else {
#pragma unroll
          for (int j = 0; j < 4; ++j)
            ((short*)Cout)[(size_t)(row + j) * N + col] = pk4[j];
        }
      } else {
#pragma unroll
        for (int j = 0; j < 4; ++j)
          ((float*)Cout)[(size_t)(row + j) * N + col] = acc[m][n][j] + bv;
      }
    }
  }
}

// ---------------- fused causal attention (r16 structure, verified 83us) ----------------
__global__ __launch_bounds__(256, 2) void k_attn(const short* __restrict__ qkv,
                                                 const short* __restrict__ vT,
                                                 short* __restrict__ out) {
  constexpr int T = 2048, C3 = 3072;
  __shared__ __align__(16) short Kl[2][64 * 72];
  __shared__ __align__(16) short P_lds[4][2][32 * 72];
  int i_ = blockIdx.x;
  int xcd = i_ & 7, m_ = i_ >> 3;
  int bh = xcd * 8 + (m_ & 7), bp = m_ >> 3;  // bijective: all 8 bp-blocks of bh on one XCD
  int batch = bh >> 4, h = bh & 15;
  int tid = threadIdx.x, w = tid >> 6, lane = tid & 63;
  int l15 = lane & 15, l4 = lane >> 4;

  int qt[2];
  qt[0] = 63 - (bp * 4 + w);
  qt[1] = bp * 4 + w;
  int lim[2] = {qt[0] >> 1, qt[1] >> 1};
  int ktb = (63 - bp * 4) >> 1;

  const short* kbase = qkv + (size_t)(batch * T) * C3 + 1024 + h * 64;
  const short* vbase = vT + (size_t)bh * 64 * T;

  int sr0 = tid >> 3, sr1 = 32 + (tid >> 3), sdc = (tid & 7) * 8;

  const float SCL = 0.18033688f;
  short8 qf[2][2][2];
#pragma unroll
  for (int t = 0; t < 2; ++t)
#pragma unroll
    for (int qc = 0; qc < 2; ++qc) {
      const short* qrow = qkv + (size_t)(batch * T + qt[t] * 32 + qc * 16 + l15) * C3 + h * 64;
#pragma unroll
      for (int kc = 0; kc < 2; ++kc) {
        short8 v = *(const short8*)(qrow + kc * 32 + l4 * 8);
#pragma unroll
        for (int i = 0; i < 8; ++i) v[i] = f2bf(bf2f(v[i]) * SCL);
        qf[t][qc][kc] = v;
      }
    }

  const f32x4 ZERO = f32x4{0.f, 0.f, 0.f, 0.f};
  short8 ONES;
#pragma unroll
  for (int i = 0; i < 8; ++i) ONES[i] = (short)0x3F80;  // bf16 1.0

  f32x4 o_[2][2][4];
  f32x4 lacc[2][2];
#pragma unroll
  for (int t = 0; t < 2; ++t)
#pragma unroll
    for (int qc = 0; qc < 2; ++qc) {
      lacc[t][qc] = ZERO;
#pragma unroll
      for (int dt = 0; dt < 4; ++dt) o_[t][qc][dt] = ZERO;
    }

  {
    short8 a = *(const short8*)(kbase + (size_t)sr0 * C3 + sdc);
    short8 b = *(const short8*)(kbase + (size_t)sr1 * C3 + sdc);
    *(short8*)&Kl[0][sr0 * 72 + sdc] = a;
    *(short8*)&Kl[0][sr1 * 72 + sdc] = b;
  }
  __syncthreads();

  int cur = 0;
  for (int kt = 0; kt <= ktb; ++kt) {
    bool more = (kt < ktb);
    bool act0 = (kt <= lim[0]), act1 = (kt <= lim[1]);

    short8 pre0, pre1;
    if (more) {
      pre0 = *(const short8*)(kbase + (size_t)((kt + 1) * 64 + sr0) * C3 + sdc);
      pre1 = *(const short8*)(kbase + (size_t)((kt + 1) * 64 + sr1) * C3 + sdc);
    }

    const short* Kb = &Kl[cur][0];
    short8 kf[4][2];
#pragma unroll
    for (int kvt = 0; kvt < 4; ++kvt)
#pragma unroll
      for (int kc = 0; kc < 2; ++kc)
        kf[kvt][kc] = *(const short8*)(Kb + (kvt * 16 + l15) * 72 + kc * 32 + l4 * 8);

    short8 vf[4][2];
#pragma unroll
    for (int dt = 0; dt < 4; ++dt)
#pragma unroll
      for (int kc = 0; kc < 2; ++kc)
        vf[dt][kc] = *(const short8*)(vbase + (size_t)(dt * 16 + l15) * T + kt * 64 + kc * 32 + l4 * 8);

    // phase A: QK + mask + softmax + pack for BOTH tiles (independent chains)
#pragma unroll
    for (int t = 0; t < 2; ++t) {
      bool act = (t == 0) ? act0 : act1;
      if (!act) continue;
      short* pb = &P_lds[w][t][0];

#pragma unroll
      for (int qc = 0; qc < 2; ++qc) {
        f32x4 s[4];
        __builtin_amdgcn_s_setprio(1);
#pragma unroll
        for (int kvt = 0; kvt < 4; ++kvt) {
          s[kvt] = __builtin_amdgcn_mfma_f32_16x16x32_bf16(kf[kvt][0], qf[t][qc][0], ZERO, 0, 0, 0);
          s[kvt] = __builtin_amdgcn_mfma_f32_16x16x32_bf16(kf[kvt][1], qf[t][qc][1], s[kvt], 0, 0, 0);
        }
        __builtin_amdgcn_s_setprio(0);

        if (kt == lim[t]) {
          int qg = qt[t] * 32 + qc * 16 + l15;
#pragma unroll
          for (int kvt = 0; kvt < 4; ++kvt)
#pragma unroll
            for (int j = 0; j < 4; ++j) {
              int kg = kt * 64 + kvt * 16 + l4 * 4 + j;
              if (kg > qg) s[kvt][j] = -1e30f;
            }
        }

#pragma unroll
        for (int kvt = 0; kvt < 4; ++kvt) {
          float p0 = exp2f(s[kvt][0]);
          float p1 = exp2f(s[kvt][1]);
          float p2 = exp2f(s[kvt][2]);
          float p3 = exp2f(s[kvt][3]);
          unsigned lo = cvt_pk_bf16(p0, p1);
          unsigned hi = cvt_pk_bf16(p2, p3);
          *(uint2v*)(pb + (qc * 16 + l15) * 72 + kvt * 16 + l4 * 4) = uint2v{lo, hi};
        }
      }
    }

    // single same-wave LDS drain for both tiles
    asm volatile("s_waitcnt lgkmcnt(0)" ::: "memory");

    // phase B: PV + l-sum for both tiles
    __builtin_amdgcn_s_setprio(1);
#pragma unroll
    for (int t = 0; t < 2; ++t) {
      bool act = (t == 0) ? act0 : act1;
      if (!act) continue;
      const short* pb = &P_lds[w][t][0];
#pragma unroll
      for (int qc = 0; qc < 2; ++qc)
#pragma unroll
        for (int kc = 0; kc < 2; ++kc) {
          short8 pf = *(const short8*)(pb + (qc * 16 + l15) * 72 + kc * 32 + l4 * 8);
          lacc[t][qc] = __builtin_amdgcn_mfma_f32_16x16x32_bf16(ONES, pf, lacc[t][qc], 0, 0, 0);
#pragma unroll
          for (int dt = 0; dt < 4; ++dt)
            o_[t][qc][dt] = __builtin_amdgcn_mfma_f32_16x16x32_bf16(vf[dt][kc], pf, o_[t][qc][dt], 0, 0, 0);
        }
    }
    __builtin_amdgcn_s_setprio(0);

    if (more) {
      *(short8*)&Kl[cur ^ 1][sr0 * 72 + sdc] = pre0;
      *(short8*)&Kl[cur ^ 1][sr1 * 72 + sdc] = pre1;
    }
    __syncthreads();
    cur ^= 1;
  }

#pragma unroll
  for (int t = 0; t < 2; ++t) {
#pragma unroll
    for (int qc = 0; qc < 2; ++qc) {
      float inv = 1.f / lacc[t][qc][0];
      size_t rowb = (size_t)(batch * T + qt[t] * 32 + qc * 16 + l15) * 1024 + h * 64;
#pragma unroll
      for (int dt = 0; dt < 4; ++dt) {
        short4v pk4;
#pragma unroll
        for (int j = 0; j < 4; ++j) pk4[j] = f2bf(o_[t][qc][dt][j] * inv);
        *(short4v*)(out + rowb + dt * 16 + l4 * 4) = pk4;
      }
    }
  }
}

extern "C" void kernel_launch(void* const* d_in, const int* in_sizes, int n_in,
                              void* d_out, int out_size, void* d_ws, size_t ws_size,
                              hipStream_t stream) {
  const float* x      = (const float*)d_in[0];
  const float* w_attn = (const float*)d_in[1];
  const float* b_attn = (const float*)d_in[2];
  const float* w_proj = (const float*)d_in[3];
  const float* b_proj = (const float*)d_in[4];
  float* out = (float*)d_out;

  char* ws = (char*)d_ws;
  short* xb   = (short*)(ws);                    // 16,777,216 B
  short* waT  = (short*)(ws + 16777216);         //  6,291,456 B
  short* wpT  = (short*)(ws + 23068672);         //  2,097,152 B
  short* qkv  = (short*)(ws + 25165824);         // 50,331,648 B
  short* vT   = (short*)(ws + 75497472);         // 16,777,216 B  (total 92,274,688)
  short* attn = xb;                              // xb dead after gemm1

  k_convert_bf16<<<4096, 256, 0, stream>>>(x, xb, 1048576);
  k_transpose_w<<<32 * 96, 256, 0, stream>>>(w_attn, waT, 1024, 3072);
  k_transpose_w<<<32 * 32, 256, 0, stream>>>(w_proj, wpT, 1024, 1024);
  k_gemm8p<true><<<768, 512, 0, stream>>>(xb, waT, b_attn, qkv, vT, 8192, 3072, 1024);
  k_attn<<<512, 256, 0, stream>>>(qkv, vT, attn);
  k_gemm8p<false><<<256, 512, 0, stream>>>(attn, wpT, b_proj, out, nullptr, 8192, 1024, 1024);
}

// Round 18
// 186.945 us; speedup vs baseline: 1.0605x; 1.0605x over previous
//
#include <hip/hip_runtime.h>

typedef short short8 __attribute__((ext_vector_type(8)));
typedef short short4v __attribute__((ext_vector_type(4)));
typedef float f32x4 __attribute__((ext_vector_type(4)));
typedef unsigned uint2v __attribute__((ext_vector_type(2)));

__device__ __forceinline__ float bf2f(short b) {
  unsigned u = ((unsigned)(unsigned short)b) << 16;
  return __builtin_bit_cast(float, u);
}
__device__ __forceinline__ short f2bf(float f) {
  unsigned u = __builtin_bit_cast(unsigned, f);
  u += 0x7fffu + ((u >> 16) & 1u);
  return (short)(u >> 16);
}
__device__ __forceinline__ unsigned cvt_pk_bf16(float lo, float hi) {
  unsigned r;
  asm("v_cvt_pk_bf16_f32 %0, %1, %2" : "=v"(r) : "v"(lo), "v"(hi));
  return r;
}

__device__ __forceinline__ void gload_lds16(const void* g, void* l) {
  __builtin_amdgcn_global_load_lds(
      (const __attribute__((address_space(1))) unsigned int*)g,
      (__attribute__((address_space(3))) unsigned int*)l, 16, 0, 0);
}

// swizzled LDS fragment read: tile rows of 64 shorts (128B), chunk = 16B unit,
// physical chunk = logical chunk ^ (row & 7)  [T2 involution]
__device__ __forceinline__ short8 lds_frag(const short* tile, int row, int kc, int l4) {
  int chunk = (kc * 4 + l4) ^ (row & 7);
  return *(const short8*)&tile[row * 64 + chunk * 8];
}

// ---------------- fp32 -> bf16 convert (x) ----------------
__global__ __launch_bounds__(256) void k_convert_bf16(const float* __restrict__ in,
                                                      short* __restrict__ out, int n8) {
  int i = blockIdx.x * 256 + threadIdx.x;
  if (i >= n8) return;
  const float4* p = (const float4*)in;
  float4 a = p[2 * i], b = p[2 * i + 1];
  short8 o;
  o[0] = f2bf(a.x); o[1] = f2bf(a.y); o[2] = f2bf(a.z); o[3] = f2bf(a.w);
  o[4] = f2bf(b.x); o[5] = f2bf(b.y); o[6] = f2bf(b.z); o[7] = f2bf(b.w);
  ((short8*)out)[i] = o;
}

// ---------------- weight transpose+convert: w[K][N] f32 -> wT[N][K] bf16 ----------------
__global__ __launch_bounds__(256) void k_transpose_w(const float* __restrict__ w,
                                                     short* __restrict__ wT, int K, int N) {
  __shared__ float t[32][33];
  int nt = N >> 5;
  int rt = blockIdx.x / nt, ct = blockIdx.x % nt;
  int tx = threadIdx.x & 31, ty = threadIdx.x >> 5;
#pragma unroll
  for (int i = 0; i < 4; ++i) {
    int r = ty * 4 + i;
    t[r][tx] = w[(size_t)(rt * 32 + r) * N + ct * 32 + tx];
  }
  __syncthreads();
#pragma unroll
  for (int i = 0; i < 4; ++i) {
    int r = ty * 4 + i;
    wT[(size_t)(ct * 32 + r) * K + rt * 32 + tx] = f2bf(t[tx][r]);
  }
}

// ---------------- GEMM 256x128, BK=64, TWO phases/K-tile (16 MFMA each) ----------------
// Fixes r17's sync-granularity regression: B frags cached in regs ph1->ph2, so per K-tile
// only 2 {ds_read | stage | barrier | lgkm0 | 16xMFMA | vmcnt | barrier} phases (4 barriers
// vs 8). Staggered race-free in-place staging: A-hi(t+1)@ph1 (last reader ph2(t-1));
// B(t+2)+A-lo(t+2)@ph2 (last readers ph1(t)). FIFO: 6 loads/tile/wave -> vmcnt(6) steady,
// tails 0/2/0. Grids: GEMM1 768=3.0/CU, GEMM2 256=1.0/CU (both %8==0, XCD swizzle bijective).
// BF16OUT (GEMM1): cols >= 2048 (V part) written transposed into vT[bh][d][tok].
template <bool BF16OUT>
__global__ __launch_bounds__(512, 1) void k_gemm8p(const short* __restrict__ A,
                                                   const short* __restrict__ Bt,
                                                   const float* __restrict__ bias,
                                                   void* __restrict__ Cout,
                                                   short* __restrict__ vTout,
                                                   int M, int N, int K) {
  __shared__ __align__(16) short Ab[2][256 * 64];
  __shared__ __align__(16) short Bb[2][128 * 64];
  int nt = N >> 7;
  int nwg = gridDim.x;
  int bid = blockIdx.x;
  int swz = (bid & 7) * (nwg >> 3) + (bid >> 3);  // nwg % 8 == 0 -> bijective
  int mt = swz / nt, ct = swz % nt;
  int tid = threadIdx.x, w = tid >> 6, lane = tid & 63;
  int l15 = lane & 15, l4 = lane >> 4;
  int wm = w >> 2, wn = w & 3;
  const short* Abase = A + (size_t)mt * 256 * K;
  const short* Bbase = Bt + (size_t)ct * 128 * K;
  int NT = K >> 6;  // assumed >= 2

  int srow = lane >> 3;
  int slc = (lane & 7) ^ srow;  // pre-swizzled source chunk (involution partner of read XOR)

  // stage one 128-row half (A: half 0/1; B: half 0 only): linear LDS dest, swizzled source
  auto stage = [&](const short* gbase, short* dstTile, int kt, int half) {
#pragma unroll
    for (int i = 0; i < 2; ++i) {
      int rowg = half * 128 + i * 64 + w * 8;
      gload_lds16(gbase + (size_t)(rowg + srow) * K + kt * 64 + slc * 8,
                  dstTile + (size_t)rowg * 64);
    }
  };

  f32x4 acc[8][2];
#pragma unroll
  for (int m = 0; m < 8; ++m)
#pragma unroll
    for (int n = 0; n < 2; ++n) acc[m][n] = f32x4{0.f, 0.f, 0.f, 0.f};

  // prologue (issue order matters for vmcnt FIFO): B0, Alo0, Ahi0, B1, Alo1 = 10 loads
  stage(Bbase, &Bb[0][0], 0, 0);
  stage(Abase, &Ab[0][0], 0, 0);
  stage(Abase, &Ab[0][0], 0, 1);
  stage(Bbase, &Bb[1][0], 1, 0);
  stage(Abase, &Ab[1][0], 1, 0);
  asm volatile("s_waitcnt vmcnt(6)" ::: "memory");  // B0 + Alo0 landed
  __builtin_amdgcn_s_barrier();

  for (int t = 0; t < NT; ++t) {
    int b = t & 1;
    const short* At = &Ab[b][0];
    const short* Btl = &Bb[b][0];
    bool p1 = (t + 1 < NT), p2 = (t + 2 < NT);

    short8 alo[4][2], ahi[4][2], bfr[2][2];

    // ===== phase 1: m-lo x n (B frags cached for ph2); stage A-hi(t+1) =====
#pragma unroll
    for (int mq = 0; mq < 4; ++mq)
#pragma unroll
      for (int kc = 0; kc < 2; ++kc)
        alo[mq][kc] = lds_frag(At, wm * 128 + mq * 16 + l15, kc, l4);
#pragma unroll
    for (int n = 0; n < 2; ++n)
#pragma unroll
      for (int kc = 0; kc < 2; ++kc)
        bfr[n][kc] = lds_frag(Btl, wn * 32 + n * 16 + l15, kc, l4);
    if (p1) stage(Abase, &Ab[(t + 1) & 1][0], t + 1, 1);  // A-hi(t+1): last reader ph2(t-1)
    __builtin_amdgcn_s_barrier();
    asm volatile("s_waitcnt lgkmcnt(0)" ::: "memory");
    __builtin_amdgcn_sched_barrier(0);
    __builtin_amdgcn_s_setprio(1);
#pragma unroll
    for (int mq = 0; mq < 4; ++mq)
#pragma unroll
      for (int n = 0; n < 2; ++n)
#pragma unroll
        for (int kc = 0; kc < 2; ++kc)
          acc[mq][n] = __builtin_amdgcn_mfma_f32_16x16x32_bf16(alo[mq][kc], bfr[n][kc], acc[mq][n], 0, 0, 0);
    __builtin_amdgcn_s_setprio(0);
    // A-hi(t) (issued ph1(t-1)) must land before ph2's ds_reads: 6 newer in flight if p1
    if (p1) {
      asm volatile("s_waitcnt vmcnt(6)" ::: "memory");
    } else {
      asm volatile("s_waitcnt vmcnt(0)" ::: "memory");
    }
    __builtin_amdgcn_s_barrier();  // ph1-end: all B + A-lo reads of tile t complete

    // ===== phase 2: m-hi x n (B from regs); stage B(t+2) + A-lo(t+2) =====
#pragma unroll
    for (int mq = 0; mq < 4; ++mq)
#pragma unroll
      for (int kc = 0; kc < 2; ++kc)
        ahi[mq][kc] = lds_frag(At, wm * 128 + 64 + mq * 16 + l15, kc, l4);
    if (p2) {
      stage(Bbase, &Bb[b][0], t + 2, 0);   // B region free since ph1-end
      stage(Abase, &Ab[b][0], t + 2, 0);   // A-lo region free since ph1-end
    }
    __builtin_amdgcn_s_barrier();
    asm volatile("s_waitcnt lgkmcnt(0)" ::: "memory");
    __builtin_amdgcn_sched_barrier(0);
    __builtin_amdgcn_s_setprio(1);
#pragma unroll
    for (int mq = 0; mq < 4; ++mq)
#pragma unroll
      for (int n = 0; n < 2; ++n)
#pragma unroll
        for (int kc = 0; kc < 2; ++kc)
          acc[4 + mq][n] = __builtin_amdgcn_mfma_f32_16x16x32_bf16(ahi[mq][kc], bfr[n][kc], acc[4 + mq][n], 0, 0, 0);
    __builtin_amdgcn_s_setprio(0);
    // B(t+1)+A-lo(t+1) (issued ph2(t-1)) must land before ph1(t+1)'s ds_reads
    if (p2) {
      asm volatile("s_waitcnt vmcnt(6)" ::: "memory");
    } else if (p1) {
      asm volatile("s_waitcnt vmcnt(2)" ::: "memory");
    }
    __builtin_amdgcn_s_barrier();  // ph2-end: all A-hi reads of tile t complete
  }

  // epilogue
#pragma unroll
  for (int m = 0; m < 8; ++m) {
#pragma unroll
    for (int n = 0; n < 2; ++n) {
      int row = mt * 256 + wm * 128 + m * 16 + l4 * 4;
      int col = ct * 128 + wn * 32 + n * 16 + l15;
      float bv = bias[col];
      if constexpr (BF16OUT) {
        short4v pk4;
#pragma unroll
        for (int j = 0; j < 4; ++j) pk4[j] = f2bf(acc[m][n][j] + bv);
        if (col >= 2048) {
          int hh = (col - 2048) >> 6, dd = (col - 2048) & 63;
          int batch2 = row >> 11, tok = row & 2047;
          *(short4v*)(vTout + (((size_t)(batch2 * 16 + hh) * 64 + dd) << 11) + tok) = pk4;
        } else {
#pragma unroll
          for (int j = 0; j < 4; ++j)
            ((short*)Cout)[(size_t)(row + j) * N + col] = pk4[j];
        }
      } else {
#pragma unroll
        for (int j = 0; j < 4; ++j)
          ((float*)Cout)[(size_t)(row + j) * N + col] = acc[m][n][j] + bv;
      }
    }
  }
}

// ---------------- fused causal attention (r16 structure, verified 83us) ----------------
__global__ __launch_bounds__(256, 2) void k_attn(const short* __restrict__ qkv,
                                                 const short* __restrict__ vT,
                                                 short* __restrict__ out) {
  constexpr int T = 2048, C3 = 3072;
  __shared__ __align__(16) short Kl[2][64 * 72];
  __shared__ __align__(16) short P_lds[4][2][32 * 72];
  int i_ = blockIdx.x;
  int xcd = i_ & 7, m_ = i_ >> 3;
  int bh = xcd * 8 + (m_ & 7), bp = m_ >> 3;  // bijective: all 8 bp-blocks of bh on one XCD
  int batch = bh >> 4, h = bh & 15;
  int tid = threadIdx.x, w = tid >> 6, lane = tid & 63;
  int l15 = lane & 15, l4 = lane >> 4;

  int qt[2];
  qt[0] = 63 - (bp * 4 + w);
  qt[1] = bp * 4 + w;
  int lim[2] = {qt[0] >> 1, qt[1] >> 1};
  int ktb = (63 - bp * 4) >> 1;

  const short* kbase = qkv + (size_t)(batch * T) * C3 + 1024 + h * 64;
  const short* vbase = vT + (size_t)bh * 64 * T;

  int sr0 = tid >> 3, sr1 = 32 + (tid >> 3), sdc = (tid & 7) * 8;

  const float SCL = 0.18033688f;
  short8 qf[2][2][2];
#pragma unroll
  for (int t = 0; t < 2; ++t)
#pragma unroll
    for (int qc = 0; qc < 2; ++qc) {
      const short* qrow = qkv + (size_t)(batch * T + qt[t] * 32 + qc * 16 + l15) * C3 + h * 64;
#pragma unroll
      for (int kc = 0; kc < 2; ++kc) {
        short8 v = *(const short8*)(qrow + kc * 32 + l4 * 8);
#pragma unroll
        for (int i = 0; i < 8; ++i) v[i] = f2bf(bf2f(v[i]) * SCL);
        qf[t][qc][kc] = v;
      }
    }

  const f32x4 ZERO = f32x4{0.f, 0.f, 0.f, 0.f};
  short8 ONES;
#pragma unroll
  for (int i = 0; i < 8; ++i) ONES[i] = (short)0x3F80;  // bf16 1.0

  f32x4 o_[2][2][4];
  f32x4 lacc[2][2];
#pragma unroll
  for (int t = 0; t < 2; ++t)
#pragma unroll
    for (int qc = 0; qc < 2; ++qc) {
      lacc[t][qc] = ZERO;
#pragma unroll
      for (int dt = 0; dt < 4; ++dt) o_[t][qc][dt] = ZERO;
    }

  {
    short8 a = *(const short8*)(kbase + (size_t)sr0 * C3 + sdc);
    short8 b = *(const short8*)(kbase + (size_t)sr1 * C3 + sdc);
    *(short8*)&Kl[0][sr0 * 72 + sdc] = a;
    *(short8*)&Kl[0][sr1 * 72 + sdc] = b;
  }
  __syncthreads();

  int cur = 0;
  for (int kt = 0; kt <= ktb; ++kt) {
    bool more = (kt < ktb);
    bool act0 = (kt <= lim[0]), act1 = (kt <= lim[1]);

    short8 pre0, pre1;
    if (more) {
      pre0 = *(const short8*)(kbase + (size_t)((kt + 1) * 64 + sr0) * C3 + sdc);
      pre1 = *(const short8*)(kbase + (size_t)((kt + 1) * 64 + sr1) * C3 + sdc);
    }

    const short* Kb = &Kl[cur][0];
    short8 kf[4][2];
#pragma unroll
    for (int kvt = 0; kvt < 4; ++kvt)
#pragma unroll
      for (int kc = 0; kc < 2; ++kc)
        kf[kvt][kc] = *(const short8*)(Kb + (kvt * 16 + l15) * 72 + kc * 32 + l4 * 8);

    short8 vf[4][2];
#pragma unroll
    for (int dt = 0; dt < 4; ++dt)
#pragma unroll
      for (int kc = 0; kc < 2; ++kc)
        vf[dt][kc] = *(const short8*)(vbase + (size_t)(dt * 16 + l15) * T + kt * 64 + kc * 32 + l4 * 8);

    // phase A: QK + mask + softmax + pack for BOTH tiles (independent chains)
#pragma unroll
    for (int t = 0; t < 2; ++t) {
      bool act = (t == 0) ? act0 : act1;
      if (!act) continue;
      short* pb = &P_lds[w][t][0];

#pragma unroll
      for (int qc = 0; qc < 2; ++qc) {
        f32x4 s[4];
        __builtin_amdgcn_s_setprio(1);
#pragma unroll
        for (int kvt = 0; kvt < 4; ++kvt) {
          s[kvt] = __builtin_amdgcn_mfma_f32_16x16x32_bf16(kf[kvt][0], qf[t][qc][0], ZERO, 0, 0, 0);
          s[kvt] = __builtin_amdgcn_mfma_f32_16x16x32_bf16(kf[kvt][1], qf[t][qc][1], s[kvt], 0, 0, 0);
        }
        __builtin_amdgcn_s_setprio(0);

        if (kt == lim[t]) {
          int qg = qt[t] * 32 + qc * 16 + l15;
#pragma unroll
          for (int kvt = 0; kvt < 4; ++kvt)
#pragma unroll
            for (int j = 0; j < 4; ++j) {
              int kg = kt * 64 + kvt * 16 + l4 * 4 + j;
              if (kg > qg) s[kvt][j] = -1e30f;
            }
        }

#pragma unroll
        for (int kvt = 0; kvt < 4; ++kvt) {
          float p0 = exp2f(s[kvt][0]);
          float p1 = exp2f(s[kvt][1]);
          float p2 = exp2f(s[kvt][2]);
          float p3 = exp2f(s[kvt][3]);
          unsigned lo = cvt_pk_bf16(p0, p1);
          unsigned hi = cvt_pk_bf16(p2, p3);
          *(uint2v*)(pb + (qc * 16 + l15) * 72 + kvt * 16 + l4 * 4) = uint2v{lo, hi};
        }
      }
    }

    // single same-wave LDS drain for both tiles
    asm volatile("s_waitcnt lgkmcnt(0)" ::: "memory");

    // phase B: PV + l-sum for both tiles
    __builtin_amdgcn_s_setprio(1);
#pragma unroll
    for (int t = 0; t < 2; ++t) {
      bool act = (t == 0) ? act0 : act1;
      if (!act) continue;
      const short* pb = &P_lds[w][t][0];
#pragma unroll
      for (int qc = 0; qc < 2; ++qc)
#pragma unroll
        for (int kc = 0; kc < 2; ++kc) {
          short8 pf = *(const short8*)(pb + (qc * 16 + l15) * 72 + kc * 32 + l4 * 8);
          lacc[t][qc] = __builtin_amdgcn_mfma_f32_16x16x32_bf16(ONES, pf, lacc[t][qc], 0, 0, 0);
#pragma unroll
          for (int dt = 0; dt < 4; ++dt)
            o_[t][qc][dt] = __builtin_amdgcn_mfma_f32_16x16x32_bf16(vf[dt][kc], pf, o_[t][qc][dt], 0, 0, 0);
        }
    }
    __builtin_amdgcn_s_setprio(0);

    if (more) {
      *(short8*)&Kl[cur ^ 1][sr0 * 72 + sdc] = pre0;
      *(short8*)&Kl[cur ^ 1][sr1 * 72 + sdc] = pre1;
    }
    __syncthreads();
    cur ^= 1;
  }

#pragma unroll
  for (int t = 0; t < 2; ++t) {
#pragma unroll
    for (int qc = 0; qc < 2; ++qc) {
      float inv = 1.f / lacc[t][qc][0];
      size_t rowb = (size_t)(batch * T + qt[t] * 32 + qc * 16 + l15) * 1024 + h * 64;
#pragma unroll
      for (int dt = 0; dt < 4; ++dt) {
        short4v pk4;
#pragma unroll
        for (int j = 0; j < 4; ++j) pk4[j] = f2bf(o_[t][qc][dt][j] * inv);
        *(short4v*)(out + rowb + dt * 16 + l4 * 4) = pk4;
      }
    }
  }
}

extern "C" void kernel_launch(void* const* d_in, const int* in_sizes, int n_in,
                              void* d_out, int out_size, void* d_ws, size_t ws_size,
                              hipStream_t stream) {
  const float* x      = (const float*)d_in[0];
  const float* w_attn = (const float*)d_in[1];
  const float* b_attn = (const float*)d_in[2];
  const float* w_proj = (const float*)d_in[3];
  const float* b_proj = (const float*)d_in[4];
  float* out = (float*)d_out;

  char* ws = (char*)d_ws;
  short* xb   = (short*)(ws);                    // 16,777,216 B
  short* waT  = (short*)(ws + 16777216);         //  6,291,456 B
  short* wpT  = (short*)(ws + 23068672);         //  2,097,152 B
  short* qkv  = (short*)(ws + 25165824);         // 50,331,648 B
  short* vT   = (short*)(ws + 75497472);         // 16,777,216 B  (total 92,274,688)
  short* attn = xb;                              // xb dead after gemm1

  k_convert_bf16<<<4096, 256, 0, stream>>>(x, xb, 1048576);
  k_transpose_w<<<32 * 96, 256, 0, stream>>>(w_attn, waT, 1024, 3072);
  k_transpose_w<<<32 * 32, 256, 0, stream>>>(w_proj, wpT, 1024, 1024);
  k_gemm8p<true><<<768, 512, 0, stream>>>(xb, waT, b_attn, qkv, vT, 8192, 3072, 1024);
  k_attn<<<512, 256, 0, stream>>>(qkv, vT, attn);
  k_gemm8p<false><<<256, 512, 0, stream>>>(attn, wpT, b_proj, out, nullptr, 8192, 1024, 1024);
}